// Round 2
// baseline (7594.171 us; speedup 1.0000x reference)
//
#include <hip/hip_runtime.h>
#include <hip/hip_bf16.h>
#include <math.h>

typedef __hip_bfloat16 bf16;

#define B_ 4
#define S_ 2048
#define H_ 768
#define NH_ 12
#define HD_ 64
#define E_ 8
#define F_ 3072
#define T_ 8192     // B_*S_
#define NA_ 16384   // T_*TOPK

__device__ __forceinline__ float b2f(bf16 v){ return __bfloat162float(v); }

__device__ __forceinline__ float4 ldA4(const float* p){ return *reinterpret_cast<const float4*>(p); }
__device__ __forceinline__ float4 ldA4(const bf16* p){
  ushort4 u = *reinterpret_cast<const ushort4*>(p);
  float4 f;
  f.x = __uint_as_float(((unsigned)u.x)<<16);
  f.y = __uint_as_float(((unsigned)u.y)<<16);
  f.z = __uint_as_float(((unsigned)u.z)<<16);
  f.w = __uint_as_float(((unsigned)u.w)<<16);
  return f;
}

__device__ __forceinline__ float block_sum256(float v, float* red){
  int tid = threadIdx.x;
  red[tid] = v; __syncthreads();
  #pragma unroll
  for (int s = 128; s > 0; s >>= 1){
    if (tid < s) red[tid] += red[tid + s];
    __syncthreads();
  }
  float r = red[0];
  __syncthreads();
  return r;
}

// ---------------- generic tiled GEMM: C(MxN,f32) = A(MxK) * B(KxN) ----------------
template<typename TA, typename TB>
__global__ __launch_bounds__(256) void gemm_k(const TA* __restrict__ A, const TB* __restrict__ Bw,
                                              float* __restrict__ C, int M, int N, int K)
{
  __shared__ float As[16][68];
  __shared__ float Bs[16][68];
  const int tid = threadIdx.x;
  const int m0 = blockIdx.y * 64, n0 = blockIdx.x * 64;
  const int ty = tid >> 4, tx = tid & 15;
  const int ar = tid >> 2, ac = (tid & 3) * 4;     // A tile: 64 rows x 16 k
  const int br = tid >> 4, bc = (tid & 15) * 4;    // B tile: 16 k x 64 cols
  float acc[4][4] = {};
  for (int k0 = 0; k0 < K; k0 += 16){
    float4 av;
    if (m0 + ar < M) av = ldA4(&A[(size_t)(m0 + ar) * K + k0 + ac]);
    else             av = make_float4(0.f,0.f,0.f,0.f);
    As[ac+0][ar] = av.x; As[ac+1][ar] = av.y; As[ac+2][ar] = av.z; As[ac+3][ar] = av.w;
    float4 bv = ldA4(&Bw[(size_t)(k0 + br) * N + n0 + bc]);
    *reinterpret_cast<float4*>(&Bs[br][bc]) = bv;
    __syncthreads();
    #pragma unroll
    for (int kk = 0; kk < 16; ++kk){
      float4 a4 = *reinterpret_cast<const float4*>(&As[kk][ty*4]);
      float4 b4 = *reinterpret_cast<const float4*>(&Bs[kk][tx*4]);
      float a[4] = {a4.x,a4.y,a4.z,a4.w};
      float b[4] = {b4.x,b4.y,b4.z,b4.w};
      #pragma unroll
      for (int i = 0; i < 4; ++i)
        #pragma unroll
        for (int j = 0; j < 4; ++j)
          acc[i][j] += a[i]*b[j];
    }
    __syncthreads();
  }
  #pragma unroll
  for (int i = 0; i < 4; ++i){
    int row = m0 + ty*4 + i;
    if (row < M)
      *reinterpret_cast<float4*>(&C[(size_t)row * N + n0 + tx*4]) =
        make_float4(acc[i][0], acc[i][1], acc[i][2], acc[i][3]);
  }
}

// ---------------- RoPE in-place on q,k inside qkv buffer ----------------
__global__ __launch_bounds__(256) void rope_k(float* __restrict__ qkv)
{
  int idx = blockIdx.x * 256 + threadIdx.x;   // < T_*NH_*32
  int j  = idx & 31;
  int hh = (idx >> 5) % NH_;
  int t  = idx / (32 * NH_);
  int s  = t & (S_ - 1);
  double invf = pow(10000.0, -(double)j / 32.0);
  float ph = (float)((double)s * invf);
  float sn, cs;
  sincosf(ph, &sn, &cs);
  float* base = qkv + (size_t)t * 2304 + hh * 192;
  float q0 = base[j],    q1 = base[32+j];
  base[j]    = q0*cs - q1*sn;
  base[32+j] = q1*cs + q0*sn;
  float k0 = base[64+j], k1 = base[96+j];
  base[64+j] = k0*cs - k1*sn;
  base[96+j] = k1*cs + k0*sn;
}

// ---------------- attention: one block = (b, h, 4 q rows) ----------------
__global__ __launch_bounds__(256) void attn_k(const float* __restrict__ qkv, const int* __restrict__ amask,
                                              float* __restrict__ ctx)
{
  __shared__ float sc[4][S_];
  __shared__ float ch[64*65];
  __shared__ float qrow[4][HD_];
  const int tid = threadIdx.x;
  const int qt = blockIdx.x & 511;
  const int hh = (blockIdx.x >> 9) % NH_;
  const int b  = blockIdx.x / (512 * NH_);
  const size_t tb = (size_t)b * S_;
  {
    int qi = tid >> 6, d = tid & 63;
    qrow[qi][d] = qkv[(tb + qt*4 + qi) * 2304 + hh*192 + d] * 0.125f;
  }
  __syncthreads();
  // scores
  for (int c = 0; c < 32; ++c){
    for (int i = tid; i < 4096; i += 256){
      int r = i >> 6, dd = i & 63;
      ch[r*65 + dd] = qkv[(tb + c*64 + r) * 2304 + hh*192 + 64 + dd];
    }
    __syncthreads();
    {
      int r = tid & 63, qi2 = tid >> 6;
      float v0 = 0.f, v1 = 0.f;
      #pragma unroll
      for (int dd = 0; dd < 64; dd += 2){
        v0 += qrow[qi2][dd]   * ch[r*65 + dd];
        v1 += qrow[qi2][dd+1] * ch[r*65 + dd+1];
      }
      float v = v0 + v1;
      int kk = c*64 + r;
      if (amask[b*S_ + kk] == 0) v = -3.3e38f;
      sc[qi2][kk] = v;
    }
    __syncthreads();
  }
  // softmax (wave per q row)
  const int qi = tid >> 6, lane = tid & 63;
  float mx = -3.4e38f;
  for (int k = lane; k < S_; k += 64) mx = fmaxf(mx, sc[qi][k]);
  #pragma unroll
  for (int o = 32; o > 0; o >>= 1) mx = fmaxf(mx, __shfl_xor(mx, o, 64));
  float sum = 0.f;
  for (int k = lane; k < S_; k += 64){
    float e = __expf(sc[qi][k] - mx);
    sc[qi][k] = e;
    sum += e;
  }
  #pragma unroll
  for (int o = 32; o > 0; o >>= 1) sum += __shfl_xor(sum, o, 64);
  float inv = 1.f / sum;
  __syncthreads();
  // PV
  float a0 = 0.f, a1 = 0.f;
  const int d = lane;
  for (int c = 0; c < 32; ++c){
    for (int i = tid; i < 4096; i += 256){
      int r = i >> 6, dd = i & 63;
      ch[r*65 + dd] = qkv[(tb + c*64 + r) * 2304 + hh*192 + 128 + dd];
    }
    __syncthreads();
    const float* sp = &sc[qi][c*64];
    #pragma unroll
    for (int r = 0; r < 64; r += 2){
      a0 += sp[r]   * ch[r*65 + d];
      a1 += sp[r+1] * ch[(r+1)*65 + d];
    }
    __syncthreads();
  }
  ctx[(tb + qt*4 + qi) * H_ + hh*HD_ + d] = (a0 + a1) * inv;
}

// ---------------- norm1: x1 = rmsnorm(x + attn_out) * w ----------------
__global__ __launch_bounds__(256) void norm1_k(const float* __restrict__ x, const float* __restrict__ ao,
                                               const float* __restrict__ w, float* __restrict__ x1)
{
  __shared__ float red[256];
  const int t = blockIdx.x, tid = threadIdx.x;
  float y[3]; float ss = 0.f;
  #pragma unroll
  for (int k = 0; k < 3; ++k){
    int i = tid + k*256;
    y[k] = x[(size_t)t*H_ + i] + ao[(size_t)t*H_ + i];
    ss += y[k]*y[k];
  }
  float tot = block_sum256(ss, red);
  float r = rsqrtf(tot / 768.f + 1.1920928955078125e-07f);
  #pragma unroll
  for (int k = 0; k < 3; ++k){
    int i = tid + k*256;
    x1[(size_t)t*H_ + i] = y[k] * r * w[i];
  }
}

// ---------------- router: logits, softmax, top-2, stats ----------------
__global__ __launch_bounds__(256) void router_k(const float* __restrict__ x1, const float* __restrict__ gw,
                                                float* __restrict__ rw, int* __restrict__ sel,
                                                float* __restrict__ Psum, int* __restrict__ cnt)
{
  __shared__ float lg[8];
  __shared__ float pr[8];
  const int t = blockIdx.x, tid = threadIdx.x;
  const int e = tid >> 5, l = tid & 31;
  const float* xr = x1 + (size_t)t * H_;
  float p = 0.f;
  for (int k = l; k < H_; k += 32) p += xr[k] * gw[k*E_ + e];
  #pragma unroll
  for (int o = 16; o > 0; o >>= 1) p += __shfl_xor(p, o, 32);
  if (l == 0) lg[e] = p;
  __syncthreads();
  if (tid == 0){
    float m = lg[0];
    #pragma unroll
    for (int i = 1; i < 8; ++i) m = fmaxf(m, lg[i]);
    float pv[8]; float s = 0.f;
    #pragma unroll
    for (int i = 0; i < 8; ++i){ pv[i] = expf(lg[i] - m); s += pv[i]; }
    float invs = 1.f / s;
    #pragma unroll
    for (int i = 0; i < 8; ++i){ pv[i] *= invs; pr[i] = pv[i]; }
    int i0 = 0;
    for (int i = 1; i < 8; ++i) if (pv[i] > pv[i0]) i0 = i;
    int i1 = -1;
    for (int i = 0; i < 8; ++i){ if (i == i0) continue; if (i1 < 0 || pv[i] > pv[i1]) i1 = i; }
    float w0 = pv[i0], w1 = pv[i1], si = 1.f / (w0 + w1);
    rw[2*t] = w0*si; rw[2*t+1] = w1*si;
    sel[2*t] = i0;   sel[2*t+1] = i1;
    atomicAdd(&cnt[i0], 1); atomicAdd(&cnt[i1], 1);
  }
  __syncthreads();
  if (tid < 8) atomicAdd(&Psum[tid], pr[tid]);
}

// ---------------- offsets + aux loss ----------------
__global__ void offs_aux_k(const float* __restrict__ Psum, const int* __restrict__ cnt,
                           int* __restrict__ offs, float* __restrict__ aux_out)
{
  __shared__ float red[8];
  const int tid = threadIdx.x;
  if (tid == 0){
    int o = 0;
    for (int e = 0; e < 8; ++e){ offs[e] = o; o += cnt[e]; }
  }
  if (tid < 8) red[tid] = ((float)cnt[tid] / 8192.f) * (Psum[tid] / 8192.f);
  __syncthreads();
  if (tid == 0){
    float s = 0.f;
    for (int e = 0; e < 8; ++e) s += red[e];
    *aux_out = 8.f * s;
  }
}

// ---------------- scatter tokens into per-expert segments ----------------
__global__ __launch_bounds__(256) void scatter_k(const int* __restrict__ sel, const int* __restrict__ offs,
                                                 int* __restrict__ cur, int* __restrict__ toka,
                                                 int* __restrict__ aidx)
{
  int t = blockIdx.x*256 + threadIdx.x;
  if (t >= T_) return;
  #pragma unroll
  for (int j = 0; j < 2; ++j){
    int e = sel[2*t + j];
    int pos = atomicAdd(&cur[e], 1);
    int a = offs[e] + pos;
    toka[a] = t;
    aidx[2*t + j] = a;
  }
}

// ---------------- MoE GEMM1 + GELU: hmid = gelu(x1_gathered @ w1[e]) ----------------
__global__ __launch_bounds__(256) void moe_gemm1_k(const float* __restrict__ X, const float* __restrict__ W1,
                                                   const int* __restrict__ offs, const int* __restrict__ cnts,
                                                   const int* __restrict__ toka, bf16* __restrict__ hmid)
{
  const int e = blockIdx.z;
  const int n_e = cnts[e];
  const int mt = blockIdx.y * 64;
  if (mt >= n_e) return;
  const int base = offs[e];
  const float* Bw = W1 + (size_t)e * H_ * F_;
  __shared__ float As[16][68];
  __shared__ float Bs[16][68];
  const int tid = threadIdx.x;
  const int n0 = blockIdx.x * 64;
  const int ty = tid >> 4, tx = tid & 15;
  const int ar = tid >> 2, ac = (tid & 3) * 4;
  const int br = tid >> 4, bc = (tid & 15) * 4;
  const int arow = mt + ar;
  const int tok = toka[base + min(arow, n_e - 1)];
  const float* Arow = X + (size_t)tok * H_;
  float acc[4][4] = {};
  for (int k0 = 0; k0 < H_; k0 += 16){
    float4 av = *reinterpret_cast<const float4*>(&Arow[k0 + ac]);
    As[ac+0][ar] = av.x; As[ac+1][ar] = av.y; As[ac+2][ar] = av.z; As[ac+3][ar] = av.w;
    float4 bv = ldA4(&Bw[(size_t)(k0 + br) * F_ + n0 + bc]);
    *reinterpret_cast<float4*>(&Bs[br][bc]) = bv;
    __syncthreads();
    #pragma unroll
    for (int kk = 0; kk < 16; ++kk){
      float4 a4 = *reinterpret_cast<const float4*>(&As[kk][ty*4]);
      float4 b4 = *reinterpret_cast<const float4*>(&Bs[kk][tx*4]);
      float a[4] = {a4.x,a4.y,a4.z,a4.w};
      float b[4] = {b4.x,b4.y,b4.z,b4.w};
      #pragma unroll
      for (int i = 0; i < 4; ++i)
        #pragma unroll
        for (int j = 0; j < 4; ++j)
          acc[i][j] += a[i]*b[j];
    }
    __syncthreads();
  }
  #pragma unroll
  for (int i = 0; i < 4; ++i){
    int row = mt + ty*4 + i;
    if (row < n_e){
      size_t o = (size_t)(base + row) * F_ + n0 + tx*4;
      #pragma unroll
      for (int j = 0; j < 4; ++j){
        float h = acc[i][j];
        float g = 0.5f * h * (1.f + erff(h * 0.70710678118654752f));
        hmid[o + j] = __float2bfloat16(g);
      }
    }
  }
}

// ---------------- MoE GEMM2: yexp = hmid @ w2[e] ----------------
__global__ __launch_bounds__(256) void moe_gemm2_k(const bf16* __restrict__ Hm, const float* __restrict__ W2,
                                                   const int* __restrict__ offs, const int* __restrict__ cnts,
                                                   float* __restrict__ yexp)
{
  const int e = blockIdx.z;
  const int n_e = cnts[e];
  const int mt = blockIdx.y * 64;
  if (mt >= n_e) return;
  const int base = offs[e];
  const float* Bw = W2 + (size_t)e * F_ * H_;
  __shared__ float As[16][68];
  __shared__ float Bs[16][68];
  const int tid = threadIdx.x;
  const int n0 = blockIdx.x * 64;
  const int ty = tid >> 4, tx = tid & 15;
  const int ar = tid >> 2, ac = (tid & 3) * 4;
  const int br = tid >> 4, bc = (tid & 15) * 4;
  const int arow = mt + ar;
  const bf16* Arow = Hm + (size_t)(base + min(arow, n_e - 1)) * F_;
  float acc[4][4] = {};
  for (int k0 = 0; k0 < F_; k0 += 16){
    float4 av = ldA4(&Arow[k0 + ac]);
    As[ac+0][ar] = av.x; As[ac+1][ar] = av.y; As[ac+2][ar] = av.z; As[ac+3][ar] = av.w;
    float4 bv = ldA4(&Bw[(size_t)(k0 + br) * H_ + n0 + bc]);
    *reinterpret_cast<float4*>(&Bs[br][bc]) = bv;
    __syncthreads();
    #pragma unroll
    for (int kk = 0; kk < 16; ++kk){
      float4 a4 = *reinterpret_cast<const float4*>(&As[kk][ty*4]);
      float4 b4 = *reinterpret_cast<const float4*>(&Bs[kk][tx*4]);
      float a[4] = {a4.x,a4.y,a4.z,a4.w};
      float b[4] = {b4.x,b4.y,b4.z,b4.w};
      #pragma unroll
      for (int i = 0; i < 4; ++i)
        #pragma unroll
        for (int j = 0; j < 4; ++j)
          acc[i][j] += a[i]*b[j];
    }
    __syncthreads();
  }
  #pragma unroll
  for (int i = 0; i < 4; ++i){
    int row = mt + ty*4 + i;
    if (row < n_e)
      *reinterpret_cast<float4*>(&yexp[(size_t)(base + row) * H_ + n0 + tx*4]) =
        make_float4(acc[i][0], acc[i][1], acc[i][2], acc[i][3]);
  }
}

// ---------------- combine MoE + residual + norm2 -> f32 out ----------------
__global__ __launch_bounds__(256) void norm2_k(const float* __restrict__ x1, const float* __restrict__ yexp,
                                               const int* __restrict__ aidx, const float* __restrict__ rw,
                                               const float* __restrict__ w, float* __restrict__ out)
{
  __shared__ float red[256];
  const int t = blockIdx.x, tid = threadIdx.x;
  const int a0 = aidx[2*t], a1 = aidx[2*t+1];
  const float w0 = rw[2*t], w1 = rw[2*t+1];
  const float* y0 = yexp + (size_t)a0 * H_;
  const float* y1 = yexp + (size_t)a1 * H_;
  const float* xr = x1 + (size_t)t * H_;
  float y[3]; float ss = 0.f;
  #pragma unroll
  for (int k = 0; k < 3; ++k){
    int i = tid + k*256;
    y[k] = xr[i] + w0*y0[i] + w1*y1[i];
    ss += y[k]*y[k];
  }
  float tot = block_sum256(ss, red);
  float r = rsqrtf(tot / 768.f + 1.1920928955078125e-07f);
  #pragma unroll
  for (int k = 0; k < 3; ++k){
    int i = tid + k*256;
    out[(size_t)t*H_ + i] = y[k] * r * w[i];
  }
}

extern "C" void kernel_launch(void* const* d_in, const int* in_sizes, int n_in,
                              void* d_out, int out_size, void* d_ws, size_t ws_size,
                              hipStream_t stream)
{
  const float* x      = (const float*)d_in[0];
  const int*   amask  = (const int*)  d_in[1];
  const float* qkv_w  = (const float*)d_in[2];
  const float* out_w  = (const float*)d_in[3];
  const float* gate_w = (const float*)d_in[4];
  const float* w1     = (const float*)d_in[5];
  const float* w2     = (const float*)d_in[6];
  const float* n1w    = (const float*)d_in[7];
  const float* n2w    = (const float*)d_in[8];

  char* ws = (char*)d_ws;
  // workspace layout (bytes), with liveness-based overlap:
  //   [0, 75497472)            qkv f32   -> later attn_out f32 (0..25165824) -> later hmid bf16
  //   [75497472, 100663296)    ctx f32   -> later hmid bf16 tail
  //   [100663296, 125829120)   x1 f32 (live to end)
  //   [125829120, 176160768)   yexp f32 (16384 x 768)
  //   [176160768, ...)         rw / sel / aidx / toka / stats
  float* qkv  = (float*)(ws);
  float* ctx  = (float*)(ws + 75497472);
  float* attn = (float*)(ws);                   // overlays dead qkv
  float* x1   = (float*)(ws + 100663296);
  float* yexp = (float*)(ws + 125829120);
  bf16*  hmid = (bf16*) (ws);                   // overlays dead qkv+ctx (exactly 100663296 B)
  float* rw   = (float*)(ws + 176160768);
  int*   sel  = (int*)  (ws + 176226304);
  int*   aidx = (int*)  (ws + 176291840);
  int*   toka = (int*)  (ws + 176357376);
  float* Psum = (float*)(ws + 176422912);
  int*   cnt  = (int*)  (ws + 176422944);
  int*   cur  = (int*)  (ws + 176422976);
  int*   offs = (int*)  (ws + 176423008);

  float* out_x2  = (float*)d_out;
  float* out_aux = out_x2 + 6291456;

  hipMemsetAsync(ws + 176422912, 0, 96, stream);  // Psum, cnt, cur

  gemm_k<float,float><<<dim3(36, 128), 256, 0, stream>>>(x, qkv_w, qkv, T_, 2304, H_);
  rope_k<<<12288, 256, 0, stream>>>(qkv);
  attn_k<<<24576, 256, 0, stream>>>(qkv, amask, ctx);
  gemm_k<float,float><<<dim3(12, 128), 256, 0, stream>>>(ctx, out_w, attn, T_, H_, H_);
  norm1_k<<<T_, 256, 0, stream>>>(x, attn, n1w, x1);
  router_k<<<T_, 256, 0, stream>>>(x1, gate_w, rw, sel, Psum, cnt);
  offs_aux_k<<<1, 64, 0, stream>>>(Psum, cnt, offs, out_aux);
  scatter_k<<<32, 256, 0, stream>>>(sel, offs, cur, toka, aidx);
  moe_gemm1_k<<<dim3(48, 256, 8), 256, 0, stream>>>(x1, w1, offs, cnt, toka, hmid);
  moe_gemm2_k<<<dim3(12, 256, 8), 256, 0, stream>>>(hmid, w2, offs, cnt, yexp);
  norm2_k<<<T_, 256, 0, stream>>>(x1, yexp, aidx, rw, n2w, out_x2);
}

// Round 3
// 3895.450 us; speedup vs baseline: 1.9495x; 1.9495x over previous
//
#include <hip/hip_runtime.h>
#include <hip/hip_bf16.h>
#include <math.h>

typedef __hip_bfloat16 bf16;

#define B_ 4
#define S_ 2048
#define H_ 768
#define NH_ 12
#define HD_ 64
#define E_ 8
#define F_ 3072
#define T_ 8192     // B_*S_
#define NA_ 16384   // T_*TOPK

__device__ __forceinline__ float b2f(bf16 v){ return __bfloat162float(v); }

__device__ __forceinline__ float4 ldA4(const float* p){ return *reinterpret_cast<const float4*>(p); }
__device__ __forceinline__ float4 ldA4(const bf16* p){
  ushort4 u = *reinterpret_cast<const ushort4*>(p);
  float4 f;
  f.x = __uint_as_float(((unsigned)u.x)<<16);
  f.y = __uint_as_float(((unsigned)u.y)<<16);
  f.z = __uint_as_float(((unsigned)u.z)<<16);
  f.w = __uint_as_float(((unsigned)u.w)<<16);
  return f;
}

__device__ __forceinline__ float block_sum256(float v, float* red){
  int tid = threadIdx.x;
  red[tid] = v; __syncthreads();
  #pragma unroll
  for (int s = 128; s > 0; s >>= 1){
    if (tid < s) red[tid] += red[tid + s];
    __syncthreads();
  }
  float r = red[0];
  __syncthreads();
  return r;
}

// ---------------- generic tiled GEMM: C(MxN,f32) = A(MxK) * B(KxN) ----------------
template<typename TA, typename TB>
__global__ __launch_bounds__(256) void gemm_k(const TA* __restrict__ A, const TB* __restrict__ Bw,
                                              float* __restrict__ C, int M, int N, int K)
{
  __shared__ float As[16][68];
  __shared__ float Bs[16][68];
  const int tid = threadIdx.x;
  const int m0 = blockIdx.y * 64, n0 = blockIdx.x * 64;
  const int ty = tid >> 4, tx = tid & 15;
  const int ar = tid >> 2, ac = (tid & 3) * 4;     // A tile: 64 rows x 16 k
  const int br = tid >> 4, bc = (tid & 15) * 4;    // B tile: 16 k x 64 cols
  float acc[4][4] = {};
  for (int k0 = 0; k0 < K; k0 += 16){
    float4 av;
    if (m0 + ar < M) av = ldA4(&A[(size_t)(m0 + ar) * K + k0 + ac]);
    else             av = make_float4(0.f,0.f,0.f,0.f);
    As[ac+0][ar] = av.x; As[ac+1][ar] = av.y; As[ac+2][ar] = av.z; As[ac+3][ar] = av.w;
    float4 bv = ldA4(&Bw[(size_t)(k0 + br) * N + n0 + bc]);
    *reinterpret_cast<float4*>(&Bs[br][bc]) = bv;
    __syncthreads();
    #pragma unroll
    for (int kk = 0; kk < 16; ++kk){
      float4 a4 = *reinterpret_cast<const float4*>(&As[kk][ty*4]);
      float4 b4 = *reinterpret_cast<const float4*>(&Bs[kk][tx*4]);
      float a[4] = {a4.x,a4.y,a4.z,a4.w};
      float b[4] = {b4.x,b4.y,b4.z,b4.w};
      #pragma unroll
      for (int i = 0; i < 4; ++i)
        #pragma unroll
        for (int j = 0; j < 4; ++j)
          acc[i][j] += a[i]*b[j];
    }
    __syncthreads();
  }
  #pragma unroll
  for (int i = 0; i < 4; ++i){
    int row = m0 + ty*4 + i;
    if (row < M)
      *reinterpret_cast<float4*>(&C[(size_t)row * N + n0 + tx*4]) =
        make_float4(acc[i][0], acc[i][1], acc[i][2], acc[i][3]);
  }
}

// ---------------- RoPE in-place on q,k inside qkv buffer ----------------
__global__ __launch_bounds__(256) void rope_k(float* __restrict__ qkv)
{
  int idx = blockIdx.x * 256 + threadIdx.x;   // < T_*NH_*32
  int j  = idx & 31;
  int hh = (idx >> 5) % NH_;
  int t  = idx / (32 * NH_);
  int s  = t & (S_ - 1);
  double invf = pow(10000.0, -(double)j / 32.0);
  float ph = (float)((double)s * invf);
  float sn, cs;
  sincosf(ph, &sn, &cs);
  float* base = qkv + (size_t)t * 2304 + hh * 192;
  float q0 = base[j],    q1 = base[32+j];
  base[j]    = q0*cs - q1*sn;
  base[32+j] = q1*cs + q0*sn;
  float k0 = base[64+j], k1 = base[96+j];
  base[64+j] = k0*cs - k1*sn;
  base[96+j] = k1*cs + k0*sn;
}

// ---------------- flash attention: one block = (b, h, 64 q rows) ----------------
// Qt[d][q], KP = Kt[d][k] during scores then Pt[k][q] during PV, Vs[k][d].
// 4x4 outer-product accumulators, online softmax, all f32.
__global__ __launch_bounds__(256) void attn_flash_k(const float* __restrict__ qkv,
                                                    const int* __restrict__ amask,
                                                    float* __restrict__ ctx)
{
  __shared__ float Qt[64][68];
  __shared__ float KP[64][68];
  __shared__ float Vs[64][64];
  const int tid = threadIdx.x;
  const int qt = blockIdx.x & 31;
  const int hh = (blockIdx.x >> 5) % NH_;
  const int b  = blockIdx.x / (32 * NH_);
  const size_t tb = (size_t)b * S_;
  const int q0 = qt * 64;
  const int ty = tid >> 4, tx = tid & 15;

  // load Q tile transposed + prescaled
  #pragma unroll
  for (int l = 0; l < 4; ++l){
    int idx = l*256 + tid;
    int r = idx >> 4, dg = (idx & 15) * 4;
    float4 v = ldA4(&qkv[(tb + q0 + r) * 2304 + hh*192 + dg]);
    Qt[dg+0][r] = v.x * 0.125f;
    Qt[dg+1][r] = v.y * 0.125f;
    Qt[dg+2][r] = v.z * 0.125f;
    Qt[dg+3][r] = v.w * 0.125f;
  }

  float O[4][4] = {};
  float m_i[4] = {-3.0e38f, -3.0e38f, -3.0e38f, -3.0e38f};
  float l_i[4] = {};

  for (int c = 0; c < 32; ++c){
    __syncthreads();   // prev PV reads of KP/Vs done (and Q load at c==0)
    #pragma unroll
    for (int l = 0; l < 4; ++l){
      int idx = l*256 + tid;
      int r = idx >> 4, dg = (idx & 15) * 4;
      const float* src = &qkv[(tb + c*64 + r) * 2304 + hh*192];
      float4 kv = ldA4(src + 64 + dg);
      KP[dg+0][r] = kv.x; KP[dg+1][r] = kv.y; KP[dg+2][r] = kv.z; KP[dg+3][r] = kv.w;
      float4 vv = ldA4(src + 128 + dg);
      *reinterpret_cast<float4*>(&Vs[r][dg]) = vv;
    }
    __syncthreads();

    // scores: S[i][j] = sum_d Qt[d][ty*4+i] * KP[d][tx*4+j]
    float s[4][4] = {};
    #pragma unroll 8
    for (int d = 0; d < 64; ++d){
      float4 qa = *reinterpret_cast<const float4*>(&Qt[d][ty*4]);
      float4 kb = *reinterpret_cast<const float4*>(&KP[d][tx*4]);
      float a[4] = {qa.x,qa.y,qa.z,qa.w};
      float bb[4] = {kb.x,kb.y,kb.z,kb.w};
      #pragma unroll
      for (int i = 0; i < 4; ++i)
        #pragma unroll
        for (int j = 0; j < 4; ++j)
          s[i][j] += a[i]*bb[j];
    }

    // mask
    const int4 mv = *reinterpret_cast<const int4*>(&amask[b*S_ + c*64 + tx*4]);
    const int mm[4] = {mv.x, mv.y, mv.z, mv.w};
    #pragma unroll
    for (int j = 0; j < 4; ++j)
      if (mm[j] == 0){
        #pragma unroll
        for (int i = 0; i < 4; ++i) s[i][j] = -3.0e38f;
      }

    // online softmax (row groups are 16 consecutive lanes: xor 1,2,4,8)
    float alpha[4];
    #pragma unroll
    for (int i = 0; i < 4; ++i){
      float rm = fmaxf(fmaxf(s[i][0], s[i][1]), fmaxf(s[i][2], s[i][3]));
      #pragma unroll
      for (int o = 8; o > 0; o >>= 1) rm = fmaxf(rm, __shfl_xor(rm, o, 64));
      float mn = fmaxf(m_i[i], rm);
      float p0 = __expf(s[i][0]-mn), p1 = __expf(s[i][1]-mn);
      float p2 = __expf(s[i][2]-mn), p3 = __expf(s[i][3]-mn);
      s[i][0]=p0; s[i][1]=p1; s[i][2]=p2; s[i][3]=p3;
      float ts = p0+p1+p2+p3;
      #pragma unroll
      for (int o = 8; o > 0; o >>= 1) ts += __shfl_xor(ts, o, 64);
      alpha[i] = __expf(m_i[i] - mn);
      m_i[i] = mn;
      l_i[i] = l_i[i]*alpha[i] + ts;
    }
    #pragma unroll
    for (int i = 0; i < 4; ++i)
      #pragma unroll
      for (int j = 0; j < 4; ++j)
        O[i][j] *= alpha[i];

    __syncthreads();   // all score reads of KP done
    // write P transposed over K: Pt[k][q]
    #pragma unroll
    for (int j = 0; j < 4; ++j)
      #pragma unroll
      for (int i = 0; i < 4; ++i)
        KP[tx*4+j][ty*4+i] = s[i][j];
    __syncthreads();

    // PV: O[i][j] += sum_k Pt[k][ty*4+i] * Vs[k][tx*4+j]
    #pragma unroll 8
    for (int k = 0; k < 64; ++k){
      float4 pa = *reinterpret_cast<const float4*>(&KP[k][ty*4]);
      float4 vb = *reinterpret_cast<const float4*>(&Vs[k][tx*4]);
      float a[4] = {pa.x,pa.y,pa.z,pa.w};
      float bb[4] = {vb.x,vb.y,vb.z,vb.w};
      #pragma unroll
      for (int i = 0; i < 4; ++i)
        #pragma unroll
        for (int j = 0; j < 4; ++j)
          O[i][j] += a[i]*bb[j];
    }
  }

  #pragma unroll
  for (int i = 0; i < 4; ++i){
    float inv = 1.f / l_i[i];
    *reinterpret_cast<float4*>(&ctx[(tb + q0 + ty*4 + i) * H_ + hh*HD_ + tx*4]) =
      make_float4(O[i][0]*inv, O[i][1]*inv, O[i][2]*inv, O[i][3]*inv);
  }
}

// ---------------- norm1: x1 = rmsnorm(x + attn_out) * w ----------------
__global__ __launch_bounds__(256) void norm1_k(const float* __restrict__ x, const float* __restrict__ ao,
                                               const float* __restrict__ w, float* __restrict__ x1)
{
  __shared__ float red[256];
  const int t = blockIdx.x, tid = threadIdx.x;
  float y[3]; float ss = 0.f;
  #pragma unroll
  for (int k = 0; k < 3; ++k){
    int i = tid + k*256;
    y[k] = x[(size_t)t*H_ + i] + ao[(size_t)t*H_ + i];
    ss += y[k]*y[k];
  }
  float tot = block_sum256(ss, red);
  float r = rsqrtf(tot / 768.f + 1.1920928955078125e-07f);
  #pragma unroll
  for (int k = 0; k < 3; ++k){
    int i = tid + k*256;
    x1[(size_t)t*H_ + i] = y[k] * r * w[i];
  }
}

// ---------------- router: logits, softmax, top-2, stats ----------------
__global__ __launch_bounds__(256) void router_k(const float* __restrict__ x1, const float* __restrict__ gw,
                                                float* __restrict__ rw, int* __restrict__ sel,
                                                float* __restrict__ Psum, int* __restrict__ cnt)
{
  __shared__ float lg[8];
  __shared__ float pr[8];
  const int t = blockIdx.x, tid = threadIdx.x;
  const int e = tid >> 5, l = tid & 31;
  const float* xr = x1 + (size_t)t * H_;
  float p = 0.f;
  for (int k = l; k < H_; k += 32) p += xr[k] * gw[k*E_ + e];
  #pragma unroll
  for (int o = 16; o > 0; o >>= 1) p += __shfl_xor(p, o, 32);
  if (l == 0) lg[e] = p;
  __syncthreads();
  if (tid == 0){
    float m = lg[0];
    #pragma unroll
    for (int i = 1; i < 8; ++i) m = fmaxf(m, lg[i]);
    float pv[8]; float s = 0.f;
    #pragma unroll
    for (int i = 0; i < 8; ++i){ pv[i] = expf(lg[i] - m); s += pv[i]; }
    float invs = 1.f / s;
    #pragma unroll
    for (int i = 0; i < 8; ++i){ pv[i] *= invs; pr[i] = pv[i]; }
    int i0 = 0;
    for (int i = 1; i < 8; ++i) if (pv[i] > pv[i0]) i0 = i;
    int i1 = -1;
    for (int i = 0; i < 8; ++i){ if (i == i0) continue; if (i1 < 0 || pv[i] > pv[i1]) i1 = i; }
    float w0 = pv[i0], w1 = pv[i1], si = 1.f / (w0 + w1);
    rw[2*t] = w0*si; rw[2*t+1] = w1*si;
    sel[2*t] = i0;   sel[2*t+1] = i1;
    atomicAdd(&cnt[i0], 1); atomicAdd(&cnt[i1], 1);
  }
  __syncthreads();
  if (tid < 8) atomicAdd(&Psum[tid], pr[tid]);
}

// ---------------- offsets + aux loss ----------------
__global__ void offs_aux_k(const float* __restrict__ Psum, const int* __restrict__ cnt,
                           int* __restrict__ offs, float* __restrict__ aux_out)
{
  __shared__ float red[8];
  const int tid = threadIdx.x;
  if (tid == 0){
    int o = 0;
    for (int e = 0; e < 8; ++e){ offs[e] = o; o += cnt[e]; }
  }
  if (tid < 8) red[tid] = ((float)cnt[tid] / 8192.f) * (Psum[tid] / 8192.f);
  __syncthreads();
  if (tid == 0){
    float s = 0.f;
    for (int e = 0; e < 8; ++e) s += red[e];
    *aux_out = 8.f * s;
  }
}

// ---------------- scatter tokens into per-expert segments ----------------
__global__ __launch_bounds__(256) void scatter_k(const int* __restrict__ sel, const int* __restrict__ offs,
                                                 int* __restrict__ cur, int* __restrict__ toka,
                                                 int* __restrict__ aidx)
{
  int t = blockIdx.x*256 + threadIdx.x;
  if (t >= T_) return;
  #pragma unroll
  for (int j = 0; j < 2; ++j){
    int e = sel[2*t + j];
    int pos = atomicAdd(&cur[e], 1);
    int a = offs[e] + pos;
    toka[a] = t;
    aidx[2*t + j] = a;
  }
}

// ---------------- MoE GEMM1 + GELU: hmid = gelu(x1_gathered @ w1[e]) ----------------
__global__ __launch_bounds__(256) void moe_gemm1_k(const float* __restrict__ X, const float* __restrict__ W1,
                                                   const int* __restrict__ offs, const int* __restrict__ cnts,
                                                   const int* __restrict__ toka, bf16* __restrict__ hmid)
{
  const int e = blockIdx.z;
  const int n_e = cnts[e];
  const int mt = blockIdx.y * 64;
  if (mt >= n_e) return;
  const int base = offs[e];
  const float* Bw = W1 + (size_t)e * H_ * F_;
  __shared__ float As[16][68];
  __shared__ float Bs[16][68];
  const int tid = threadIdx.x;
  const int n0 = blockIdx.x * 64;
  const int ty = tid >> 4, tx = tid & 15;
  const int ar = tid >> 2, ac = (tid & 3) * 4;
  const int br = tid >> 4, bc = (tid & 15) * 4;
  const int arow = mt + ar;
  const int tok = toka[base + min(arow, n_e - 1)];
  const float* Arow = X + (size_t)tok * H_;
  float acc[4][4] = {};
  for (int k0 = 0; k0 < H_; k0 += 16){
    float4 av = *reinterpret_cast<const float4*>(&Arow[k0 + ac]);
    As[ac+0][ar] = av.x; As[ac+1][ar] = av.y; As[ac+2][ar] = av.z; As[ac+3][ar] = av.w;
    float4 bv = ldA4(&Bw[(size_t)(k0 + br) * F_ + n0 + bc]);
    *reinterpret_cast<float4*>(&Bs[br][bc]) = bv;
    __syncthreads();
    #pragma unroll
    for (int kk = 0; kk < 16; ++kk){
      float4 a4 = *reinterpret_cast<const float4*>(&As[kk][ty*4]);
      float4 b4 = *reinterpret_cast<const float4*>(&Bs[kk][tx*4]);
      float a[4] = {a4.x,a4.y,a4.z,a4.w};
      float b[4] = {b4.x,b4.y,b4.z,b4.w};
      #pragma unroll
      for (int i = 0; i < 4; ++i)
        #pragma unroll
        for (int j = 0; j < 4; ++j)
          acc[i][j] += a[i]*b[j];
    }
    __syncthreads();
  }
  #pragma unroll
  for (int i = 0; i < 4; ++i){
    int row = mt + ty*4 + i;
    if (row < n_e){
      size_t o = (size_t)(base + row) * F_ + n0 + tx*4;
      #pragma unroll
      for (int j = 0; j < 4; ++j){
        float h = acc[i][j];
        float g = 0.5f * h * (1.f + erff(h * 0.70710678118654752f));
        hmid[o + j] = __float2bfloat16(g);
      }
    }
  }
}

// ---------------- MoE GEMM2: yexp = hmid @ w2[e] ----------------
__global__ __launch_bounds__(256) void moe_gemm2_k(const bf16* __restrict__ Hm, const float* __restrict__ W2,
                                                   const int* __restrict__ offs, const int* __restrict__ cnts,
                                                   float* __restrict__ yexp)
{
  const int e = blockIdx.z;
  const int n_e = cnts[e];
  const int mt = blockIdx.y * 64;
  if (mt >= n_e) return;
  const int base = offs[e];
  const float* Bw = W2 + (size_t)e * F_ * H_;
  __shared__ float As[16][68];
  __shared__ float Bs[16][68];
  const int tid = threadIdx.x;
  const int n0 = blockIdx.x * 64;
  const int ty = tid >> 4, tx = tid & 15;
  const int ar = tid >> 2, ac = (tid & 3) * 4;
  const int br = tid >> 4, bc = (tid & 15) * 4;
  const int arow = mt + ar;
  const bf16* Arow = Hm + (size_t)(base + min(arow, n_e - 1)) * F_;
  float acc[4][4] = {};
  for (int k0 = 0; k0 < F_; k0 += 16){
    float4 av = ldA4(&Arow[k0 + ac]);
    As[ac+0][ar] = av.x; As[ac+1][ar] = av.y; As[ac+2][ar] = av.z; As[ac+3][ar] = av.w;
    float4 bv = ldA4(&Bw[(size_t)(k0 + br) * H_ + n0 + bc]);
    *reinterpret_cast<float4*>(&Bs[br][bc]) = bv;
    __syncthreads();
    #pragma unroll
    for (int kk = 0; kk < 16; ++kk){
      float4 a4 = *reinterpret_cast<const float4*>(&As[kk][ty*4]);
      float4 b4 = *reinterpret_cast<const float4*>(&Bs[kk][tx*4]);
      float a[4] = {a4.x,a4.y,a4.z,a4.w};
      float b[4] = {b4.x,b4.y,b4.z,b4.w};
      #pragma unroll
      for (int i = 0; i < 4; ++i)
        #pragma unroll
        for (int j = 0; j < 4; ++j)
          acc[i][j] += a[i]*b[j];
    }
    __syncthreads();
  }
  #pragma unroll
  for (int i = 0; i < 4; ++i){
    int row = mt + ty*4 + i;
    if (row < n_e)
      *reinterpret_cast<float4*>(&yexp[(size_t)(base + row) * H_ + n0 + tx*4]) =
        make_float4(acc[i][0], acc[i][1], acc[i][2], acc[i][3]);
  }
}

// ---------------- combine MoE + residual + norm2 -> f32 out ----------------
__global__ __launch_bounds__(256) void norm2_k(const float* __restrict__ x1, const float* __restrict__ yexp,
                                               const int* __restrict__ aidx, const float* __restrict__ rw,
                                               const float* __restrict__ w, float* __restrict__ out)
{
  __shared__ float red[256];
  const int t = blockIdx.x, tid = threadIdx.x;
  const int a0 = aidx[2*t], a1 = aidx[2*t+1];
  const float w0 = rw[2*t], w1 = rw[2*t+1];
  const float* y0 = yexp + (size_t)a0 * H_;
  const float* y1 = yexp + (size_t)a1 * H_;
  const float* xr = x1 + (size_t)t * H_;
  float y[3]; float ss = 0.f;
  #pragma unroll
  for (int k = 0; k < 3; ++k){
    int i = tid + k*256;
    y[k] = xr[i] + w0*y0[i] + w1*y1[i];
    ss += y[k]*y[k];
  }
  float tot = block_sum256(ss, red);
  float r = rsqrtf(tot / 768.f + 1.1920928955078125e-07f);
  #pragma unroll
  for (int k = 0; k < 3; ++k){
    int i = tid + k*256;
    out[(size_t)t*H_ + i] = y[k] * r * w[i];
  }
}

extern "C" void kernel_launch(void* const* d_in, const int* in_sizes, int n_in,
                              void* d_out, int out_size, void* d_ws, size_t ws_size,
                              hipStream_t stream)
{
  const float* x      = (const float*)d_in[0];
  const int*   amask  = (const int*)  d_in[1];
  const float* qkv_w  = (const float*)d_in[2];
  const float* out_w  = (const float*)d_in[3];
  const float* gate_w = (const float*)d_in[4];
  const float* w1     = (const float*)d_in[5];
  const float* w2     = (const float*)d_in[6];
  const float* n1w    = (const float*)d_in[7];
  const float* n2w    = (const float*)d_in[8];

  char* ws = (char*)d_ws;
  float* qkv  = (float*)(ws);
  float* ctx  = (float*)(ws + 75497472);
  float* attn = (float*)(ws);                   // overlays dead qkv
  float* x1   = (float*)(ws + 100663296);
  float* yexp = (float*)(ws + 125829120);
  bf16*  hmid = (bf16*) (ws);                   // overlays dead qkv+ctx
  float* rw   = (float*)(ws + 176160768);
  int*   sel  = (int*)  (ws + 176226304);
  int*   aidx = (int*)  (ws + 176291840);
  int*   toka = (int*)  (ws + 176357376);
  float* Psum = (float*)(ws + 176422912);
  int*   cnt  = (int*)  (ws + 176422944);
  int*   cur  = (int*)  (ws + 176422976);
  int*   offs = (int*)  (ws + 176423008);

  float* out_x2  = (float*)d_out;
  float* out_aux = out_x2 + 6291456;

  hipMemsetAsync(ws + 176422912, 0, 96, stream);  // Psum, cnt, cur

  gemm_k<float,float><<<dim3(36, 128), 256, 0, stream>>>(x, qkv_w, qkv, T_, 2304, H_);
  rope_k<<<12288, 256, 0, stream>>>(qkv);
  attn_flash_k<<<1536, 256, 0, stream>>>(qkv, amask, ctx);
  gemm_k<float,float><<<dim3(12, 128), 256, 0, stream>>>(ctx, out_w, attn, T_, H_, H_);
  norm1_k<<<T_, 256, 0, stream>>>(x, attn, n1w, x1);
  router_k<<<T_, 256, 0, stream>>>(x1, gate_w, rw, sel, Psum, cnt);
  offs_aux_k<<<1, 64, 0, stream>>>(Psum, cnt, offs, out_aux);
  scatter_k<<<32, 256, 0, stream>>>(sel, offs, cur, toka, aidx);
  moe_gemm1_k<<<dim3(48, 256, 8), 256, 0, stream>>>(x1, w1, offs, cnt, toka, hmid);
  moe_gemm2_k<<<dim3(12, 256, 8), 256, 0, stream>>>(hmid, w2, offs, cnt, yexp);
  norm2_k<<<T_, 256, 0, stream>>>(x1, yexp, aidx, rw, n2w, out_x2);
}

// Round 4
// 2279.505 us; speedup vs baseline: 3.3315x; 1.7089x over previous
//
#include <hip/hip_runtime.h>
#include <hip/hip_bf16.h>
#include <math.h>

typedef __hip_bfloat16 bf16;
typedef __attribute__((ext_vector_type(8))) short bf16x8;
typedef __attribute__((ext_vector_type(4))) float f32x4;

#define B_ 4
#define S_ 2048
#define H_ 768
#define NH_ 12
#define HD_ 64
#define E_ 8
#define F_ 3072
#define T_ 8192     // B_*S_

__device__ __forceinline__ unsigned f2bf(float x){   // RNE f32->bf16 bits
  unsigned u = __float_as_uint(x);
  return (u + 0x7FFFu + ((u >> 16) & 1u)) >> 16;
}

__device__ __forceinline__ float4 ldA4(const float* p){ return *reinterpret_cast<const float4*>(p); }

__device__ __forceinline__ float block_sum256(float v, float* red){
  int tid = threadIdx.x;
  red[tid] = v; __syncthreads();
  #pragma unroll
  for (int s = 128; s > 0; s >>= 1){
    if (tid < s) red[tid] += red[tid + s];
    __syncthreads();
  }
  float r = red[0];
  __syncthreads();
  return r;
}

// ---------------- generic tiled GEMM (f32 VALU): C = A * B ----------------
__global__ __launch_bounds__(256) void gemm_k(const float* __restrict__ A, const float* __restrict__ Bw,
                                              float* __restrict__ C, int M, int N, int K)
{
  __shared__ float As[16][68];
  __shared__ float Bs[16][68];
  const int tid = threadIdx.x;
  const int m0 = blockIdx.y * 64, n0 = blockIdx.x * 64;
  const int ty = tid >> 4, tx = tid & 15;
  const int ar = tid >> 2, ac = (tid & 3) * 4;
  const int br = tid >> 4, bc = (tid & 15) * 4;
  float acc[4][4] = {};
  for (int k0 = 0; k0 < K; k0 += 16){
    float4 av = ldA4(&A[(size_t)(m0 + ar) * K + k0 + ac]);
    As[ac+0][ar] = av.x; As[ac+1][ar] = av.y; As[ac+2][ar] = av.z; As[ac+3][ar] = av.w;
    float4 bv = ldA4(&Bw[(size_t)(k0 + br) * N + n0 + bc]);
    *reinterpret_cast<float4*>(&Bs[br][bc]) = bv;
    __syncthreads();
    #pragma unroll
    for (int kk = 0; kk < 16; ++kk){
      float4 a4 = *reinterpret_cast<const float4*>(&As[kk][ty*4]);
      float4 b4 = *reinterpret_cast<const float4*>(&Bs[kk][tx*4]);
      float a[4] = {a4.x,a4.y,a4.z,a4.w};
      float b[4] = {b4.x,b4.y,b4.z,b4.w};
      #pragma unroll
      for (int i = 0; i < 4; ++i)
        #pragma unroll
        for (int j = 0; j < 4; ++j)
          acc[i][j] += a[i]*b[j];
    }
    __syncthreads();
  }
  #pragma unroll
  for (int i = 0; i < 4; ++i){
    int row = m0 + ty*4 + i;
    *reinterpret_cast<float4*>(&C[(size_t)row * N + n0 + tx*4]) =
      make_float4(acc[i][0], acc[i][1], acc[i][2], acc[i][3]);
  }
}

// ---------------- RoPE in-place on q,k inside qkv buffer ----------------
__global__ __launch_bounds__(256) void rope_k(float* __restrict__ qkv)
{
  int idx = blockIdx.x * 256 + threadIdx.x;
  int j  = idx & 31;
  int hh = (idx >> 5) % NH_;
  int t  = idx / (32 * NH_);
  int s  = t & (S_ - 1);
  double invf = pow(10000.0, -(double)j / 32.0);
  float ph = (float)((double)s * invf);
  float sn, cs;
  sincosf(ph, &sn, &cs);
  float* base = qkv + (size_t)t * 2304 + hh * 192;
  float q0 = base[j],    q1 = base[32+j];
  base[j]    = q0*cs - q1*sn;
  base[32+j] = q1*cs + q0*sn;
  float k0 = base[64+j], k1 = base[96+j];
  base[64+j] = k0*cs - k1*sn;
  base[96+j] = k1*cs + k0*sn;
}

// ---------------- flash attention (f32 VALU), one block = (b,h,64 q rows) ----------------
__global__ __launch_bounds__(256) void attn_flash_k(const float* __restrict__ qkv,
                                                    const int* __restrict__ amask,
                                                    float* __restrict__ ctx)
{
  __shared__ float Qt[64][68];
  __shared__ float KP[64][68];
  __shared__ float Vs[64][64];
  const int tid = threadIdx.x;
  const int qt = blockIdx.x & 31;
  const int hh = (blockIdx.x >> 5) % NH_;
  const int b  = blockIdx.x / (32 * NH_);
  const size_t tb = (size_t)b * S_;
  const int q0 = qt * 64;
  const int ty = tid >> 4, tx = tid & 15;

  #pragma unroll
  for (int l = 0; l < 4; ++l){
    int idx = l*256 + tid;
    int r = idx >> 4, dg = (idx & 15) * 4;
    float4 v = ldA4(&qkv[(tb + q0 + r) * 2304 + hh*192 + dg]);
    Qt[dg+0][r] = v.x * 0.125f;
    Qt[dg+1][r] = v.y * 0.125f;
    Qt[dg+2][r] = v.z * 0.125f;
    Qt[dg+3][r] = v.w * 0.125f;
  }

  float O[4][4] = {};
  float m_i[4] = {-3.0e38f, -3.0e38f, -3.0e38f, -3.0e38f};
  float l_i[4] = {};

  for (int c = 0; c < 32; ++c){
    __syncthreads();
    #pragma unroll
    for (int l = 0; l < 4; ++l){
      int idx = l*256 + tid;
      int r = idx >> 4, dg = (idx & 15) * 4;
      const float* src = &qkv[(tb + c*64 + r) * 2304 + hh*192];
      float4 kv = ldA4(src + 64 + dg);
      KP[dg+0][r] = kv.x; KP[dg+1][r] = kv.y; KP[dg+2][r] = kv.z; KP[dg+3][r] = kv.w;
      float4 vv = ldA4(src + 128 + dg);
      *reinterpret_cast<float4*>(&Vs[r][dg]) = vv;
    }
    __syncthreads();

    float s[4][4] = {};
    #pragma unroll 8
    for (int d = 0; d < 64; ++d){
      float4 qa = *reinterpret_cast<const float4*>(&Qt[d][ty*4]);
      float4 kb = *reinterpret_cast<const float4*>(&KP[d][tx*4]);
      float a[4] = {qa.x,qa.y,qa.z,qa.w};
      float bb[4] = {kb.x,kb.y,kb.z,kb.w};
      #pragma unroll
      for (int i = 0; i < 4; ++i)
        #pragma unroll
        for (int j = 0; j < 4; ++j)
          s[i][j] += a[i]*bb[j];
    }

    const int4 mv = *reinterpret_cast<const int4*>(&amask[b*S_ + c*64 + tx*4]);
    const int mm[4] = {mv.x, mv.y, mv.z, mv.w};
    #pragma unroll
    for (int j = 0; j < 4; ++j)
      if (mm[j] == 0){
        #pragma unroll
        for (int i = 0; i < 4; ++i) s[i][j] = -3.0e38f;
      }

    float alpha[4];
    #pragma unroll
    for (int i = 0; i < 4; ++i){
      float rm = fmaxf(fmaxf(s[i][0], s[i][1]), fmaxf(s[i][2], s[i][3]));
      #pragma unroll
      for (int o = 8; o > 0; o >>= 1) rm = fmaxf(rm, __shfl_xor(rm, o, 64));
      float mn = fmaxf(m_i[i], rm);
      float p0 = __expf(s[i][0]-mn), p1 = __expf(s[i][1]-mn);
      float p2 = __expf(s[i][2]-mn), p3 = __expf(s[i][3]-mn);
      s[i][0]=p0; s[i][1]=p1; s[i][2]=p2; s[i][3]=p3;
      float ts = p0+p1+p2+p3;
      #pragma unroll
      for (int o = 8; o > 0; o >>= 1) ts += __shfl_xor(ts, o, 64);
      alpha[i] = __expf(m_i[i] - mn);
      m_i[i] = mn;
      l_i[i] = l_i[i]*alpha[i] + ts;
    }
    #pragma unroll
    for (int i = 0; i < 4; ++i)
      #pragma unroll
      for (int j = 0; j < 4; ++j)
        O[i][j] *= alpha[i];

    __syncthreads();
    #pragma unroll
    for (int j = 0; j < 4; ++j)
      #pragma unroll
      for (int i = 0; i < 4; ++i)
        KP[tx*4+j][ty*4+i] = s[i][j];
    __syncthreads();

    #pragma unroll 8
    for (int k = 0; k < 64; ++k){
      float4 pa = *reinterpret_cast<const float4*>(&KP[k][ty*4]);
      float4 vb = *reinterpret_cast<const float4*>(&Vs[k][tx*4]);
      float a[4] = {pa.x,pa.y,pa.z,pa.w};
      float bb[4] = {vb.x,vb.y,vb.z,vb.w};
      #pragma unroll
      for (int i = 0; i < 4; ++i)
        #pragma unroll
        for (int j = 0; j < 4; ++j)
          O[i][j] += a[i]*bb[j];
    }
  }

  #pragma unroll
  for (int i = 0; i < 4; ++i){
    float inv = 1.f / l_i[i];
    *reinterpret_cast<float4*>(&ctx[(tb + q0 + ty*4 + i) * H_ + hh*HD_ + tx*4]) =
      make_float4(O[i][0]*inv, O[i][1]*inv, O[i][2]*inv, O[i][3]*inv);
  }
}

// ---------------- norm1: x1 = rmsnorm(x + attn_out) * w ----------------
__global__ __launch_bounds__(256) void norm1_k(const float* __restrict__ x, const float* __restrict__ ao,
                                               const float* __restrict__ w, float* __restrict__ x1)
{
  __shared__ float red[256];
  const int t = blockIdx.x, tid = threadIdx.x;
  float y[3]; float ss = 0.f;
  #pragma unroll
  for (int k = 0; k < 3; ++k){
    int i = tid + k*256;
    y[k] = x[(size_t)t*H_ + i] + ao[(size_t)t*H_ + i];
    ss += y[k]*y[k];
  }
  float tot = block_sum256(ss, red);
  float r = rsqrtf(tot / 768.f + 1.1920928955078125e-07f);
  #pragma unroll
  for (int k = 0; k < 3; ++k){
    int i = tid + k*256;
    x1[(size_t)t*H_ + i] = y[k] * r * w[i];
  }
}

// ---------------- router: logits, softmax, top-2, stats ----------------
__global__ __launch_bounds__(256) void router_k(const float* __restrict__ x1, const float* __restrict__ gw,
                                                float* __restrict__ rw, int* __restrict__ sel,
                                                float* __restrict__ Psum, int* __restrict__ cnt)
{
  __shared__ float lg[8];
  __shared__ float pr[8];
  const int t = blockIdx.x, tid = threadIdx.x;
  const int e = tid >> 5, l = tid & 31;
  const float* xr = x1 + (size_t)t * H_;
  float p = 0.f;
  for (int k = l; k < H_; k += 32) p += xr[k] * gw[k*E_ + e];
  #pragma unroll
  for (int o = 16; o > 0; o >>= 1) p += __shfl_xor(p, o, 32);
  if (l == 0) lg[e] = p;
  __syncthreads();
  if (tid == 0){
    float m = lg[0];
    #pragma unroll
    for (int i = 1; i < 8; ++i) m = fmaxf(m, lg[i]);
    float pv[8]; float s = 0.f;
    #pragma unroll
    for (int i = 0; i < 8; ++i){ pv[i] = expf(lg[i] - m); s += pv[i]; }
    float invs = 1.f / s;
    #pragma unroll
    for (int i = 0; i < 8; ++i){ pv[i] *= invs; pr[i] = pv[i]; }
    int i0 = 0;
    for (int i = 1; i < 8; ++i) if (pv[i] > pv[i0]) i0 = i;
    int i1 = -1;
    for (int i = 0; i < 8; ++i){ if (i == i0) continue; if (i1 < 0 || pv[i] > pv[i1]) i1 = i; }
    float w0 = pv[i0], w1 = pv[i1], si = 1.f / (w0 + w1);
    rw[2*t] = w0*si; rw[2*t+1] = w1*si;
    sel[2*t] = i0;   sel[2*t+1] = i1;
    atomicAdd(&cnt[i0], 1); atomicAdd(&cnt[i1], 1);
  }
  __syncthreads();
  if (tid < 8) atomicAdd(&Psum[tid], pr[tid]);
}

// ---------------- offsets + aux loss ----------------
__global__ void offs_aux_k(const float* __restrict__ Psum, const int* __restrict__ cnt,
                           int* __restrict__ offs, float* __restrict__ aux_out)
{
  __shared__ float red[8];
  const int tid = threadIdx.x;
  if (tid == 0){
    int o = 0;
    for (int e = 0; e < 8; ++e){ offs[e] = o; o += cnt[e]; }
  }
  if (tid < 8) red[tid] = ((float)cnt[tid] / 8192.f) * (Psum[tid] / 8192.f);
  __syncthreads();
  if (tid == 0){
    float s = 0.f;
    for (int e = 0; e < 8; ++e) s += red[e];
    *aux_out = 8.f * s;
  }
}

// ---------------- scatter tokens into per-expert segments (+ per-assignment weight) ----------------
__global__ __launch_bounds__(256) void scatter_k(const int* __restrict__ sel, const int* __restrict__ offs,
                                                 const float* __restrict__ rw,
                                                 int* __restrict__ cur, int* __restrict__ toka,
                                                 float* __restrict__ wgt)
{
  int t = blockIdx.x*256 + threadIdx.x;
  if (t >= T_) return;
  #pragma unroll
  for (int j = 0; j < 2; ++j){
    int e = sel[2*t + j];
    int pos = atomicAdd(&cur[e], 1);
    int a = offs[e] + pos;
    toka[a] = t;
    wgt[a] = rw[2*t + j];
  }
}

// ---------------- tiled transpose + f32->bf16 convert: dst[C][R] = src[R][C] ----------------
__global__ __launch_bounds__(256) void transpose_conv_k(const float* __restrict__ src,
                                                        unsigned short* __restrict__ dst,
                                                        int R, int C)
{
  __shared__ float T[32][33];
  const float* s = src + (size_t)blockIdx.z * R * C;
  unsigned short* d = dst + (size_t)blockIdx.z * R * C;
  int r0 = blockIdx.y*32, c0 = blockIdx.x*32;
  int t = threadIdx.x;
  int r = t >> 3, c4 = (t & 7) * 4;
  float4 v = ldA4(&s[(size_t)(r0+r)*C + c0 + c4]);
  T[r][c4+0]=v.x; T[r][c4+1]=v.y; T[r][c4+2]=v.z; T[r][c4+3]=v.w;
  __syncthreads();
  int c = t >> 3, r4 = (t & 7) * 4;
  ushort4 o;
  o.x = (unsigned short)f2bf(T[r4+0][c]);
  o.y = (unsigned short)f2bf(T[r4+1][c]);
  o.z = (unsigned short)f2bf(T[r4+2][c]);
  o.w = (unsigned short)f2bf(T[r4+3][c]);
  *reinterpret_cast<ushort4*>(&d[(size_t)(c0+c)*R + r0 + r4]) = o;
}

// ---------------- MoE GEMM1 (MFMA bf16): hmid = gelu(x1[toka] @ w1T^T) ----------------
// 128x128 tile, BK=64, 4 waves; A staged f32->bf16 on the fly; B pre-transposed [F][H] bf16.
__global__ __launch_bounds__(256) void moe1_mfma_k(const float* __restrict__ X,
                                                   const unsigned short* __restrict__ Bt,
                                                   const int* __restrict__ offs,
                                                   const int* __restrict__ cnts,
                                                   const int* __restrict__ toka,
                                                   unsigned short* __restrict__ hmid)
{
  const int e = blockIdx.z;
  const int n_e = cnts[e];
  const int mt = blockIdx.y * 128;
  if (mt >= n_e) return;
  const int base = offs[e];
  const unsigned short* Bw = Bt + (size_t)e * (H_*F_);
  __shared__ __align__(16) short Al[8*129*8];
  __shared__ __align__(16) short Bl[8*129*8];
  const int tid = threadIdx.x;
  const int n0 = blockIdx.x * 128;
  int tokm[4];
  #pragma unroll
  for (int i = 0; i < 4; ++i){
    int m = (tid + i*256) >> 3;
    tokm[i] = toka[base + min(mt + m, n_e - 1)];
  }
  const int lane = tid & 63, w = tid >> 6;
  const int wr = w >> 1, wc = w & 1;
  const int quad = lane >> 4, l15 = lane & 15;
  f32x4 acc[4][4];
  #pragma unroll
  for (int a = 0; a < 4; ++a)
    #pragma unroll
    for (int b = 0; b < 4; ++b) acc[a][b] = (f32x4){0.f,0.f,0.f,0.f};

  for (int k0 = 0; k0 < H_; k0 += 64){
    __syncthreads();
    #pragma unroll
    for (int i = 0; i < 4; ++i){
      int c = tid + i*256;
      int m = c >> 3, kc = c & 7;
      const float* src = X + (size_t)tokm[i]*H_ + k0 + kc*8;
      float4 f0 = ldA4(src);
      float4 f1 = ldA4(src + 4);
      int4 pk;
      pk.x = (int)(f2bf(f0.x) | (f2bf(f0.y) << 16));
      pk.y = (int)(f2bf(f0.z) | (f2bf(f0.w) << 16));
      pk.z = (int)(f2bf(f1.x) | (f2bf(f1.y) << 16));
      pk.w = (int)(f2bf(f1.z) | (f2bf(f1.w) << 16));
      *reinterpret_cast<int4*>(&Al[(kc*129 + m)*8]) = pk;
      *reinterpret_cast<int4*>(&Bl[(kc*129 + m)*8]) =
        *reinterpret_cast<const int4*>(&Bw[(size_t)(n0 + m)*H_ + k0 + kc*8]);
    }
    __syncthreads();
    #pragma unroll
    for (int ks = 0; ks < 2; ++ks){
      bf16x8 af[4], bfr[4];
      #pragma unroll
      for (int mi = 0; mi < 4; ++mi)
        af[mi] = *reinterpret_cast<const bf16x8*>(&Al[((ks*4+quad)*129 + wr*64 + mi*16 + l15)*8]);
      #pragma unroll
      for (int ni = 0; ni < 4; ++ni)
        bfr[ni] = *reinterpret_cast<const bf16x8*>(&Bl[((ks*4+quad)*129 + wc*64 + ni*16 + l15)*8]);
      #pragma unroll
      for (int mi = 0; mi < 4; ++mi)
        #pragma unroll
        for (int ni = 0; ni < 4; ++ni)
          acc[mi][ni] = __builtin_amdgcn_mfma_f32_16x16x32_bf16(af[mi], bfr[ni], acc[mi][ni], 0, 0, 0);
    }
  }
  #pragma unroll
  for (int mi = 0; mi < 4; ++mi)
    #pragma unroll
    for (int r = 0; r < 4; ++r){
      int row = mt + wr*64 + mi*16 + quad*4 + r;
      if (row < n_e){
        unsigned short* dst = hmid + (size_t)(base + row)*F_ + n0 + wc*64 + l15;
        #pragma unroll
        for (int ni = 0; ni < 4; ++ni){
          float h = acc[mi][ni][r];
          float g = 0.5f * h * (1.f + erff(h * 0.70710678118654752f));
          dst[ni*16] = (unsigned short)f2bf(g);
        }
      }
    }
}

// ---------------- MoE GEMM2 (MFMA bf16): x1 += wgt * (hmid @ w2T^T) ----------------
__global__ __launch_bounds__(256) void moe2_mfma_k(const unsigned short* __restrict__ Hm,
                                                   const unsigned short* __restrict__ Bt,
                                                   const int* __restrict__ offs,
                                                   const int* __restrict__ cnts,
                                                   const int* __restrict__ toka,
                                                   const float* __restrict__ wgt,
                                                   float* __restrict__ x1acc)
{
  const int e = blockIdx.z;
  const int n_e = cnts[e];
  const int mt = blockIdx.y * 128;
  if (mt >= n_e) return;
  const int base = offs[e];
  const unsigned short* Bw = Bt + (size_t)e * (H_*F_);
  __shared__ __align__(16) short Al[8*129*8];
  __shared__ __align__(16) short Bl[8*129*8];
  const int tid = threadIdx.x;
  const int n0 = blockIdx.x * 128;
  const int lane = tid & 63, w = tid >> 6;
  const int wr = w >> 1, wc = w & 1;
  const int quad = lane >> 4, l15 = lane & 15;
  f32x4 acc[4][4];
  #pragma unroll
  for (int a = 0; a < 4; ++a)
    #pragma unroll
    for (int b = 0; b < 4; ++b) acc[a][b] = (f32x4){0.f,0.f,0.f,0.f};

  for (int k0 = 0; k0 < F_; k0 += 64){
    __syncthreads();
    #pragma unroll
    for (int i = 0; i < 4; ++i){
      int c = tid + i*256;
      int m = c >> 3, kc = c & 7;
      int hrow = base + min(mt + m, n_e - 1);
      *reinterpret_cast<int4*>(&Al[(kc*129 + m)*8]) =
        *reinterpret_cast<const int4*>(&Hm[(size_t)hrow*F_ + k0 + kc*8]);
      *reinterpret_cast<int4*>(&Bl[(kc*129 + m)*8]) =
        *reinterpret_cast<const int4*>(&Bw[(size_t)(n0 + m)*F_ + k0 + kc*8]);
    }
    __syncthreads();
    #pragma unroll
    for (int ks = 0; ks < 2; ++ks){
      bf16x8 af[4], bfr[4];
      #pragma unroll
      for (int mi = 0; mi < 4; ++mi)
        af[mi] = *reinterpret_cast<const bf16x8*>(&Al[((ks*4+quad)*129 + wr*64 + mi*16 + l15)*8]);
      #pragma unroll
      for (int ni = 0; ni < 4; ++ni)
        bfr[ni] = *reinterpret_cast<const bf16x8*>(&Bl[((ks*4+quad)*129 + wc*64 + ni*16 + l15)*8]);
      #pragma unroll
      for (int mi = 0; mi < 4; ++mi)
        #pragma unroll
        for (int ni = 0; ni < 4; ++ni)
          acc[mi][ni] = __builtin_amdgcn_mfma_f32_16x16x32_bf16(af[mi], bfr[ni], acc[mi][ni], 0, 0, 0);
    }
  }
  #pragma unroll
  for (int mi = 0; mi < 4; ++mi)
    #pragma unroll
    for (int r = 0; r < 4; ++r){
      int row = mt + wr*64 + mi*16 + quad*4 + r;
      if (row < n_e){
        int tok = toka[base + row];
        float wg = wgt[base + row];
        float* dst = x1acc + (size_t)tok*H_ + n0 + wc*64 + l15;
        #pragma unroll
        for (int ni = 0; ni < 4; ++ni)
          atomicAdd(&dst[ni*16], acc[mi][ni][r] * wg);
      }
    }
}

// ---------------- norm2: out = rmsnorm(x1_accumulated) * w ----------------
__global__ __launch_bounds__(256) void norm2_k(const float* __restrict__ x1acc,
                                               const float* __restrict__ w, float* __restrict__ out)
{
  __shared__ float red[256];
  const int t = blockIdx.x, tid = threadIdx.x;
  const float* xr = x1acc + (size_t)t * H_;
  float y[3]; float ss = 0.f;
  #pragma unroll
  for (int k = 0; k < 3; ++k){
    int i = tid + k*256;
    y[k] = xr[i];
    ss += y[k]*y[k];
  }
  float tot = block_sum256(ss, red);
  float r = rsqrtf(tot / 768.f + 1.1920928955078125e-07f);
  #pragma unroll
  for (int k = 0; k < 3; ++k){
    int i = tid + k*256;
    out[(size_t)t*H_ + i] = y[k] * r * w[i];
  }
}

extern "C" void kernel_launch(void* const* d_in, const int* in_sizes, int n_in,
                              void* d_out, int out_size, void* d_ws, size_t ws_size,
                              hipStream_t stream)
{
  const float* x      = (const float*)d_in[0];
  const int*   amask  = (const int*)  d_in[1];
  const float* qkv_w  = (const float*)d_in[2];
  const float* out_w  = (const float*)d_in[3];
  const float* gate_w = (const float*)d_in[4];
  const float* w1     = (const float*)d_in[5];
  const float* w2     = (const float*)d_in[6];
  const float* n1w    = (const float*)d_in[7];
  const float* n2w    = (const float*)d_in[8];

  char* ws = (char*)d_ws;
  // workspace layout (bytes), liveness-overlapped; total ~163.8 MB:
  //   [0, 75497472)            qkv f32 (P1-P3) -> attn f32 [0,25165824) (P4-P5) -> hmid bf16 [0,100663296) (P7-P8)
  //   [75497472, 100663296)    ctx f32 (P3-P4) -> hmid tail
  //   [100663296, 125829120)   x1 f32 (norm1 -> router/moe1; moe2 atomically accumulates; norm2 reads)
  //   [125829120, 163577856)   w1T bf16 (conv -> moe1), then w2T bf16 (conv -> moe2)
  //   [163577856, ...)         rw / sel / toka / wgt / stats
  float* qkv  = (float*)(ws);
  float* ctx  = (float*)(ws + 75497472);
  float* attn = (float*)(ws);
  float* x1   = (float*)(ws + 100663296);
  unsigned short* hmid = (unsigned short*)(ws);
  unsigned short* w1T  = (unsigned short*)(ws + 125829120);
  unsigned short* w2T  = (unsigned short*)(ws + 125829120);
  float* rw   = (float*)(ws + 163577856);
  int*   sel  = (int*)  (ws + 163643392);
  int*   toka = (int*)  (ws + 163708928);
  float* wgt  = (float*)(ws + 163774464);
  float* Psum = (float*)(ws + 163840000);
  int*   cnt  = (int*)  (ws + 163840032);
  int*   cur  = (int*)  (ws + 163840064);
  int*   offs = (int*)  (ws + 163840096);

  float* out_x2  = (float*)d_out;
  float* out_aux = out_x2 + 6291456;

  hipMemsetAsync(ws + 163840000, 0, 128, stream);  // Psum, cnt, cur, offs

  gemm_k<<<dim3(36, 128), 256, 0, stream>>>(x, qkv_w, qkv, T_, 2304, H_);
  rope_k<<<12288, 256, 0, stream>>>(qkv);
  attn_flash_k<<<1536, 256, 0, stream>>>(qkv, amask, ctx);
  gemm_k<<<dim3(12, 128), 256, 0, stream>>>(ctx, out_w, attn, T_, H_, H_);
  norm1_k<<<T_, 256, 0, stream>>>(x, attn, n1w, x1);
  router_k<<<T_, 256, 0, stream>>>(x1, gate_w, rw, sel, Psum, cnt);
  offs_aux_k<<<1, 64, 0, stream>>>(Psum, cnt, offs, out_aux);
  scatter_k<<<32, 256, 0, stream>>>(sel, offs, rw, cur, toka, wgt);
  transpose_conv_k<<<dim3(96, 24, 8), 256, 0, stream>>>(w1, w1T, H_, F_);   // w1T[e][F][H]
  moe1_mfma_k<<<dim3(24, 64, 8), 256, 0, stream>>>(x1, w1T, offs, cnt, toka, hmid);
  transpose_conv_k<<<dim3(24, 96, 8), 256, 0, stream>>>(w2, w2T, F_, H_);   // w2T[e][H][F]
  moe2_mfma_k<<<dim3(6, 64, 8), 256, 0, stream>>>(hmid, w2T, offs, cnt, toka, wgt, x1);
  norm2_k<<<T_, 256, 0, stream>>>(x1, n2w, out_x2);
}